// Round 1
// 458.704 us; speedup vs baseline: 1.0144x; 1.0144x over previous
//
#include <hip/hip_runtime.h>
#include <hip/hip_bf16.h>

// Problem constants
#define N 8192
#define NEMB 256
#define NHID 64
#define LOG2E 1.4426950408889634f

typedef __attribute__((ext_vector_type(8))) short short8;   // 8 bf16 (4 VGPRs)
typedef __attribute__((ext_vector_type(4))) float f32x4;    // 4 fp32

__device__ __forceinline__ float elu_f(float x) {
    return x > 0.f ? x : __expf(x) - 1.f;
}

__device__ __forceinline__ float exp2_fast(float x) {
#if __has_builtin(__builtin_amdgcn_exp2f)
    return __builtin_amdgcn_exp2f(x);
#else
    return exp2f(x);
#endif
}

__device__ __forceinline__ short f2bf(float f) {
    union { float f; unsigned u; } c; c.f = f;
    unsigned r = c.u + 0x7fffu + ((c.u >> 16) & 1u);   // RNE
    return (short)(r >> 16);
}

__device__ __forceinline__ float bf2f(short s) {
    union { unsigned u; float f; } c; c.u = ((unsigned)(unsigned short)s) << 16;
    return c.f;
}

// ---------------------------------------------------------------------------
// K01: fused independent prologue work.
//  blocks [0, N):        adj row -> 64-bit mask words + per-row popcount
//  blocks [N, N+N/4):    h = x@Ww + Wb -> hT bf16 [64][8192]; fs = h@a1; fd = h@a2
// ---------------------------------------------------------------------------
__global__ __launch_bounds__(256) void k01_prologue(
    const int* __restrict__ adj, unsigned long long* __restrict__ bits,
    unsigned int* __restrict__ cnt,
    const float* __restrict__ x, const float* __restrict__ Ww,
    const float* __restrict__ Wb, const float* __restrict__ a1,
    const float* __restrict__ a2, short* __restrict__ hT,
    float* __restrict__ fs, float* __restrict__ fd)
{
    int t = threadIdx.x;
    if (blockIdx.x < N) {
        // ---- k1 part: bitmask build ----
        int row = blockIdx.x;
        int lane = t & 63;
        const int* arow = adj + (size_t)row * N;
        unsigned long long* brow = bits + (size_t)row * (N / 64);
        __shared__ unsigned int wcs[16];
        unsigned int c = 0;
        for (int it = 0; it < 8; it++) {
            int j = it * 1024 + t * 4;
            int4 a = *(const int4*)&arow[j];
            unsigned int nb = (unsigned)(a.x > 0) | ((unsigned)(a.y > 0) << 1) |
                              ((unsigned)(a.z > 0) << 2) | ((unsigned)(a.w > 0) << 3);
            unsigned int v8  = nb  | (__shfl_down((int)nb, 1, 64) << 4);
            unsigned int v16 = v8  | (__shfl_down((int)v8, 2, 64) << 8);
            unsigned int v32 = v16 | (__shfl_down((int)v16, 4, 64) << 16);
            unsigned int hi  = (unsigned int)__shfl_down((int)v32, 8, 64);
            if ((lane & 15) == 0) {
                unsigned long long word = (unsigned long long)v32 |
                                          ((unsigned long long)hi << 32);
                brow[it * 16 + (t >> 4)] = word;
                c += __popcll(word);
            }
        }
        if ((t & 15) == 0) wcs[t >> 4] = c;
        __syncthreads();
        if (t == 0) {
            unsigned int s = 0;
            for (int i = 0; i < 16; i++) s += wcs[i];
            cnt[row] = s;
        }
    } else {
        // ---- k0 part: h, fs, fd ----
        __shared__ float xs[4 * NEMB];
        int rowblk = (blockIdx.x - N) * 4;
        *(float4*)&xs[t * 4] = *(const float4*)&x[(size_t)rowblk * NEMB + t * 4];
        __syncthreads();
        int rl = t >> 6;     // wave id = row
        int k  = t & 63;     // lane = output column
        float acc = Wb[k];
        const float* xrow = &xs[rl * NEMB];
#pragma unroll 8
        for (int c = 0; c < NEMB; c++)
            acc = fmaf(xrow[c], Ww[c * NHID + k], acc);
        int row = rowblk + rl;
        hT[(size_t)k * N + row] = f2bf(acc);
        float s1 = acc * a1[k];
        float s2 = acc * a2[k];
        for (int o = 32; o > 0; o >>= 1) {
            s1 += __shfl_down(s1, o, 64);
            s2 += __shfl_down(s2, o, 64);
        }
        if (k == 0) { fs[row] = s1; fd[row] = s2; }
    }
}

// ---------------------------------------------------------------------------
// K4: out = elu( (P_unnorm @ h) / rowsum ).  bf16 MFMA, A-frags generated
// in-register from the bitmask.  p_hat = exp(lrelu(fs_i+fd_j+ab)),
// computed as exp2(lrelu(s' + d')) with log2e folded into the staged tables
// (lrelu is positively homogeneous).  Per-bit fs lookup replaced by a
// cmp/cndmask against the (single possible) 8192-rank window crossing R*.
// This round: row-sums via 5th MFMA against all-ones B (VALU -> MFMA pipe),
// bf16 pack via v_cvt_pk_bf16_f32 (4 ops vs 12), paired prefix-popc loads,
// dred halved to 16 KB (LDS 66 -> 50.7 KB for occupancy headroom).
// ---------------------------------------------------------------------------
#define SEGW 16  // 64-bit words per segment (16*64 = 1024 cols)

__global__ __launch_bounds__(512, 4) void k4_mfma(
    const unsigned long long* __restrict__ bits,
    const unsigned int* __restrict__ cnt,
    const float* __restrict__ fs, const float* __restrict__ fd,
    const float* __restrict__ ab, const short* __restrict__ hT,
    float* __restrict__ out)
{
    __shared__ float fdl[N];             // 32 KB (fd * log2e)
    __shared__ float dred[4 * 1024];     // 16 KB: per-wave-pair partial D tiles
    __shared__ float fsl[32];            // (fs + ab) * log2e window
    __shared__ float rsum[8 * 16];
    __shared__ unsigned int red512[512]; // 2 KB: rowbase reduction
    __shared__ unsigned int rb16[16];    // per-row rank bases

    int t = threadIdx.x;
    int bid = blockIdx.x;
    int wv = t >> 6;          // wave id = K-segment 0..7
    int L = t & 63;
    int m = L & 15;           // A-row within tile / B-col within tile
    int g = L >> 4;           // k-octet group 0..3
    int m0 = bid * 16;
    int row = m0 + m;
    float ab0 = ab[0];

    // stage fd*log2e into LDS (8192 floats)
    for (int i = 0; i < 4; ++i) {
        int fi = i * 2048 + t * 4;
        float4 v4 = *(const float4*)&fd[fi];
        v4.x *= LOG2E; v4.y *= LOG2E; v4.z *= LOG2E; v4.w *= LOG2E;
        *(float4*)&fdl[fi] = v4;
    }
    // in-block rowbase: Sum cnt[0..m0). Thread t owns rows 16t..16t+15.
    unsigned int c16 = 0;
    if (t < bid) {
        const uint4* cp = (const uint4*)(cnt + t * 16);
        uint4 q0 = cp[0], q1 = cp[1], q2 = cp[2], q3 = cp[3];
        c16 = q0.x + q0.y + q0.z + q0.w + q1.x + q1.y + q1.z + q1.w +
              q2.x + q2.y + q2.z + q2.w + q3.x + q3.y + q3.z + q3.w;
    }
    red512[t] = c16;
    __syncthreads();
#pragma unroll
    for (int o = 256; o > 0; o >>= 1) {
        if (t < o) red512[t] += red512[t + o];
        __syncthreads();
    }
    unsigned int rowbase0 = red512[0];
    if (t == 0) {
        unsigned int s = rowbase0;
#pragma unroll
        for (int i = 0; i < 16; ++i) { rb16[i] = s; s += cnt[m0 + i]; }
    }
    unsigned int fs0 = rowbase0 >> 13;
    if (t < 32) {
        unsigned int idx = fs0 + (unsigned)t;
        if (idx > 8191u) idx = 8191u;
        fsl[t] = (fs[idx] + ab0) * LOG2E;
    }
    __syncthreads();

    // per-row fs window: row spans <= 8192 ranks -> at most one crossing
    unsigned int rbm = rb16[m];
    unsigned int w13 = rbm >> 13;
    float s0 = fsl[w13 - fs0];
    unsigned int i1 = w13 + 1 - fs0; if (i1 > 31u) i1 = 31u;
    float s1 = fsl[i1];
    unsigned int Rstar = (w13 + 1u) << 13;   // first rank using s1

    const unsigned long long* brow = bits + (size_t)row * (N / 64);
    int w0 = wv * SEGW;
    // segment start rank base for this row: rbm + popc(words [0,w0))
    // paired loads: lane g covers word residues {2g, 2g+1} mod 8
    unsigned int part = 0;
    for (int w = g * 2; w < w0; w += 8) {
        unsigned long long pb0 = brow[w];
        unsigned long long pb1 = brow[w + 1];
        part += (unsigned)__popcll(pb0) + (unsigned)__popcll(pb1);
    }
    part += __shfl_xor(part, 16, 64);
    part += __shfl_xor(part, 32, 64);
    unsigned int base = rbm + part;

    // all-ones bf16 B-fragment for MFMA row-sums
    short8 ones8;
#pragma unroll
    for (int k = 0; k < 8; ++k) ones8[k] = (short)0x3f80;

    f32x4 acc0 = {0.f,0.f,0.f,0.f}, acc1 = {0.f,0.f,0.f,0.f};
    f32x4 acc2 = {0.f,0.f,0.f,0.f}, acc3 = {0.f,0.f,0.f,0.f};
    f32x4 acc4 = {0.f,0.f,0.f,0.f};
    const short* hpm = hT + (size_t)m * N;

    for (int w = w0; w < w0 + SEGW; ++w) {
        unsigned long long w64 = brow[w];
#pragma unroll
        for (int hh = 0; hh < 2; ++hh) {
            int off = hh * 32 + g * 8;
            unsigned int n = (unsigned)__popcll(w64 & ((1ull << off) - 1ull));
            unsigned int u = (unsigned int)(w64 >> off) & 0xffu;
            float pf[8];
#pragma unroll
            for (int j = 0; j < 8; ++j) {
                unsigned int bit = (u >> j) & 1u;
                unsigned int r = base + n;
                float d = fdl[r & 8191u];
                float sv = (r >= Rstar) ? s1 : s0;
                float v = sv + d;
                float lr = fmaxf(v, 0.01f * v);     // leaky_relu (both signs)
                float p = exp2_fast(lr);
                pf[j] = bit ? p : 0.f;
                n += bit;
            }
            union { short8 v; unsigned q[4]; } afu;
#pragma unroll
            for (int k = 0; k < 4; ++k) {
                unsigned qk;
                asm("v_cvt_pk_bf16_f32 %0, %1, %2"
                    : "=v"(qk) : "v"(pf[2 * k]), "v"(pf[2 * k + 1]));
                afu.q[k] = qk;
            }
            const short* hp = hpm + w * 64 + off;
            short8 b0 = *(const short8*)(hp);
            short8 b1 = *(const short8*)(hp + 16 * N);
            short8 b2 = *(const short8*)(hp + 32 * N);
            short8 b3 = *(const short8*)(hp + 48 * N);
            acc0 = __builtin_amdgcn_mfma_f32_16x16x32_bf16(afu.v, b0, acc0, 0, 0, 0);
            acc1 = __builtin_amdgcn_mfma_f32_16x16x32_bf16(afu.v, b1, acc1, 0, 0, 0);
            acc2 = __builtin_amdgcn_mfma_f32_16x16x32_bf16(afu.v, b2, acc2, 0, 0, 0);
            acc3 = __builtin_amdgcn_mfma_f32_16x16x32_bf16(afu.v, b3, acc3, 0, 0, 0);
            acc4 = __builtin_amdgcn_mfma_f32_16x16x32_bf16(afu.v, ones8, acc4, 0, 0, 0);
        }
        base += (unsigned)__popcll(w64);
    }

    // row sums from the ones-MFMA: D cols are all identical; lanes with m==0
    // hold rowsum[g*4+reg] in acc4[reg].
    if (m == 0) {
#pragma unroll
        for (int reg = 0; reg < 4; ++reg)
            rsum[wv * 16 + g * 4 + reg] = acc4[reg];
    }

    // D tile layout: col = lane&15, row = (lane>>4)*4 + reg
    // waves 0-3 write their tiles; waves 4-7 accumulate into them (barriered)
    float* dw = &dred[(wv & 3) * 1024];
    if (wv < 4) {
#pragma unroll
        for (int reg = 0; reg < 4; ++reg) {
            int lrow = g * 4 + reg;
            dw[lrow * 64 + m     ] = acc0[reg];
            dw[lrow * 64 + m + 16] = acc1[reg];
            dw[lrow * 64 + m + 32] = acc2[reg];
            dw[lrow * 64 + m + 48] = acc3[reg];
        }
    }
    __syncthreads();
    if (wv >= 4) {
#pragma unroll
        for (int reg = 0; reg < 4; ++reg) {
            int lrow = g * 4 + reg;
            dw[lrow * 64 + m     ] += acc0[reg];
            dw[lrow * 64 + m + 16] += acc1[reg];
            dw[lrow * 64 + m + 32] += acc2[reg];
            dw[lrow * 64 + m + 48] += acc3[reg];
        }
    }
    __syncthreads();

    // reduce 4 tile-pairs, normalize, elu, store: 1024 outputs / 512 threads
#pragma unroll
    for (int qq = 0; qq < 2; ++qq) {
        int o = qq * 512 + t;
        int lrow = o >> 6, col = o & 63;
        float s = 0.f;
#pragma unroll
        for (int v4 = 0; v4 < 4; ++v4) s += dred[v4 * 1024 + o];
        float rs = 0.f;
#pragma unroll
        for (int v8 = 0; v8 < 8; ++v8) rs += rsum[v8 * 16 + lrow];
        int grow = m0 + lrow;
        float res;
        if (cnt[grow] == 0u) {
            // empty row: softmax over all -inf = uniform 1/N (never hit for
            // this input; kept for faithful semantics)
            float hs = 0.f;
            const short* hp = hT + (size_t)col * N;
            for (int j = 0; j < N; ++j) hs += bf2f(hp[j]);
            res = hs * (1.0f / 8192.0f);
        } else {
            res = s / rs;
        }
        out[(size_t)grow * NHID + col] = elu_f(res);
    }
}

// ---------------------------------------------------------------------------
extern "C" void kernel_launch(void* const* d_in, const int* in_sizes, int n_in,
                              void* d_out, int out_size, void* d_ws, size_t ws_size,
                              hipStream_t stream)
{
    const float* x   = (const float*)d_in[0];
    const int*   adj = (const int*)d_in[1];
    const float* Ww  = (const float*)d_in[2];
    const float* Wb  = (const float*)d_in[3];
    const float* a1  = (const float*)d_in[4];
    const float* a2  = (const float*)d_in[5];
    const float* ab  = (const float*)d_in[6];
    float* out = (float*)d_out;

    char* ws = (char*)d_ws;
    float* fs = (float*)(ws + 0);                          // 32 KB
    float* fd = (float*)(ws + 32768);                      // 32 KB
    unsigned int* cnt = (unsigned int*)(ws + 65536);       // 32 KB
    short* hT = (short*)(ws + 98304);                      // 1 MB bf16 [64][8192]
    unsigned long long* bits = (unsigned long long*)(ws + 98304 + 1048576); // 8 MB

    k01_prologue<<<N + N / 4, 256, 0, stream>>>(adj, bits, cnt,
                                                x, Ww, Wb, a1, a2, hT, fs, fd);
    k4_mfma<<<N / 16, 512, 0, stream>>>(bits, cnt, fs, fd, ab, hT, out);
}

// Round 2
// 456.933 us; speedup vs baseline: 1.0183x; 1.0039x over previous
//
#include <hip/hip_runtime.h>
#include <hip/hip_bf16.h>

// Problem constants
#define N 8192
#define NEMB 256
#define NHID 64
#define LOG2E 1.4426950408889634f

typedef __attribute__((ext_vector_type(8))) short short8;   // 8 bf16 (4 VGPRs)
typedef __attribute__((ext_vector_type(4))) float f32x4;    // 4 fp32

__device__ __forceinline__ float elu_f(float x) {
    return x > 0.f ? x : __expf(x) - 1.f;
}

__device__ __forceinline__ float exp2_fast(float x) {
#if __has_builtin(__builtin_amdgcn_exp2f)
    return __builtin_amdgcn_exp2f(x);
#else
    return exp2f(x);
#endif
}

__device__ __forceinline__ short f2bf(float f) {
    union { float f; unsigned u; } c; c.f = f;
    unsigned r = c.u + 0x7fffu + ((c.u >> 16) & 1u);   // RNE
    return (short)(r >> 16);
}

__device__ __forceinline__ float bf2f(short s) {
    union { unsigned u; float f; } c; c.u = ((unsigned)(unsigned short)s) << 16;
    return c.f;
}

// ---------------------------------------------------------------------------
// K01: fused independent prologue work.
//  blocks [0, N):        adj row -> 64-bit mask words via __ballot (no shfl
//                        pack), per-segment popcounts (ushort[8]) + row count
//  blocks [N, N+N/4):    h = x@Ww + Wb -> hT bf16 [64][8192]; fs = h@a1; fd = h@a2
// ---------------------------------------------------------------------------
__global__ __launch_bounds__(256) void k01_prologue(
    const int* __restrict__ adj, unsigned long long* __restrict__ bits,
    unsigned int* __restrict__ cnt, unsigned short* __restrict__ segcnt,
    const float* __restrict__ x, const float* __restrict__ Ww,
    const float* __restrict__ Wb, const float* __restrict__ a1,
    const float* __restrict__ a2, short* __restrict__ hT,
    float* __restrict__ fs, float* __restrict__ fd)
{
    int t = threadIdx.x;
    if (blockIdx.x < N) {
        // ---- k1 part: bitmask build via ballot ----
        int row = blockIdx.x;
        int lane = t & 63;
        int wv4 = t >> 6;    // wave 0..3
        const int* arow = adj + (size_t)row * N;
        unsigned long long* brow = bits + (size_t)row * (N / 64);
        __shared__ unsigned int wseg[8][4];
        __shared__ unsigned int ssum[8];
#pragma unroll
        for (int it = 0; it < 8; ++it) {
            // wave wv4 covers ints [it*1024 + wv4*256, +256) -> words
            // [it*16 + wv4*4, +4).  Segment 'it' == words [it*16, it*16+16).
            int o = it * 1024 + wv4 * 256 + lane;
            int a0 = arow[o];
            int a1v = arow[o + 64];
            int a2v = arow[o + 128];
            int a3v = arow[o + 192];
            unsigned long long b0 = __ballot(a0 > 0);
            unsigned long long b1 = __ballot(a1v > 0);
            unsigned long long b2 = __ballot(a2v > 0);
            unsigned long long b3 = __ballot(a3v > 0);
            unsigned long long w = (lane == 0) ? b0 : (lane == 1) ? b1 :
                                   (lane == 2) ? b2 : b3;
            if (lane < 4) brow[it * 16 + wv4 * 4 + lane] = w;
            unsigned int pc = (unsigned)(__popcll(b0) + __popcll(b1) +
                                         __popcll(b2) + __popcll(b3));
            if (lane == 0) wseg[it][wv4] = pc;
        }
        __syncthreads();
        if (t < 8) {
            unsigned int s = wseg[t][0] + wseg[t][1] + wseg[t][2] + wseg[t][3];
            segcnt[(size_t)row * 8 + t] = (unsigned short)s;
            ssum[t] = s;
        }
        __syncthreads();
        if (t == 0) {
            unsigned int s = 0;
#pragma unroll
            for (int i = 0; i < 8; ++i) s += ssum[i];
            cnt[row] = s;
        }
    } else {
        // ---- k0 part: h, fs, fd ----
        __shared__ float xs[4 * NEMB];
        int rowblk = (blockIdx.x - N) * 4;
        *(float4*)&xs[t * 4] = *(const float4*)&x[(size_t)rowblk * NEMB + t * 4];
        __syncthreads();
        int rl = t >> 6;     // wave id = row
        int k  = t & 63;     // lane = output column
        float acc = Wb[k];
        const float* xrow = &xs[rl * NEMB];
#pragma unroll 8
        for (int c = 0; c < NEMB; c++)
            acc = fmaf(xrow[c], Ww[c * NHID + k], acc);
        int row = rowblk + rl;
        hT[(size_t)k * N + row] = f2bf(acc);
        float s1 = acc * a1[k];
        float s2 = acc * a2[k];
        for (int o = 32; o > 0; o >>= 1) {
            s1 += __shfl_down(s1, o, 64);
            s2 += __shfl_down(s2, o, 64);
        }
        if (k == 0) { fs[row] = s1; fd[row] = s2; }
    }
}

// ---------------------------------------------------------------------------
// K4: out = elu( (P_unnorm @ h) / rowsum ).  bf16 MFMA, A-frags generated
// in-register from the bitmask.  p_hat = exp(lrelu(fs_i+fd_j+ab)),
// computed as exp2(lrelu(s' + d')) with log2e folded into the staged tables
// (lrelu is positively homogeneous).  Per-bit fs lookup replaced by a
// cmp/cndmask against the (single possible) 8192-rank window crossing R*.
// Row-sums via 5th MFMA against all-ones B; bf16 pack via v_cvt_pk_bf16_f32.
// This round: per-wave segment base from precomputed segcnt (uint4 load +
// 8 predicated adds) replaces the serialized prefix-popcount scan.
// ---------------------------------------------------------------------------
#define SEGW 16  // 64-bit words per segment (16*64 = 1024 cols)

__global__ __launch_bounds__(512, 4) void k4_mfma(
    const unsigned long long* __restrict__ bits,
    const unsigned int* __restrict__ cnt,
    const unsigned short* __restrict__ segcnt,
    const float* __restrict__ fs, const float* __restrict__ fd,
    const float* __restrict__ ab, const short* __restrict__ hT,
    float* __restrict__ out)
{
    __shared__ float fdl[N];             // 32 KB (fd * log2e)
    __shared__ float dred[4 * 1024];     // 16 KB: per-wave-pair partial D tiles
    __shared__ float fsl[32];            // (fs + ab) * log2e window
    __shared__ float rsum[8 * 16];
    __shared__ unsigned int red512[512]; // 2 KB: rowbase reduction
    __shared__ unsigned int rb16[16];    // per-row rank bases

    int t = threadIdx.x;
    int bid = blockIdx.x;
    int wv = t >> 6;          // wave id = K-segment 0..7
    int L = t & 63;
    int m = L & 15;           // A-row within tile / B-col within tile
    int g = L >> 4;           // k-octet group 0..3
    int m0 = bid * 16;
    int row = m0 + m;
    float ab0 = ab[0];

    // stage fd*log2e into LDS (8192 floats)
    for (int i = 0; i < 4; ++i) {
        int fi = i * 2048 + t * 4;
        float4 v4 = *(const float4*)&fd[fi];
        v4.x *= LOG2E; v4.y *= LOG2E; v4.z *= LOG2E; v4.w *= LOG2E;
        *(float4*)&fdl[fi] = v4;
    }
    // in-block rowbase: Sum cnt[0..m0). Thread t owns rows 16t..16t+15.
    unsigned int c16 = 0;
    if (t < bid) {
        const uint4* cp = (const uint4*)(cnt + t * 16);
        uint4 q0 = cp[0], q1 = cp[1], q2 = cp[2], q3 = cp[3];
        c16 = q0.x + q0.y + q0.z + q0.w + q1.x + q1.y + q1.z + q1.w +
              q2.x + q2.y + q2.z + q2.w + q3.x + q3.y + q3.z + q3.w;
    }
    red512[t] = c16;
    __syncthreads();
#pragma unroll
    for (int o = 256; o > 0; o >>= 1) {
        if (t < o) red512[t] += red512[t + o];
        __syncthreads();
    }
    unsigned int rowbase0 = red512[0];
    if (t == 0) {
        unsigned int s = rowbase0;
#pragma unroll
        for (int i = 0; i < 16; ++i) { rb16[i] = s; s += cnt[m0 + i]; }
    }
    unsigned int fs0 = rowbase0 >> 13;
    if (t < 32) {
        unsigned int idx = fs0 + (unsigned)t;
        if (idx > 8191u) idx = 8191u;
        fsl[t] = (fs[idx] + ab0) * LOG2E;
    }
    __syncthreads();

    // per-row fs window: row spans <= 8192 ranks -> at most one crossing
    unsigned int rbm = rb16[m];
    unsigned int w13 = rbm >> 13;
    float s0 = fsl[w13 - fs0];
    unsigned int i1 = w13 + 1 - fs0; if (i1 > 31u) i1 = 31u;
    float s1 = fsl[i1];
    unsigned int Rstar = (w13 + 1u) << 13;   // first rank using s1

    const unsigned long long* brow = bits + (size_t)row * (N / 64);
    int w0 = wv * SEGW;
    // segment start rank base: rbm + prefix of per-segment counts
    uint4 scv = *(const uint4*)(segcnt + (size_t)row * 8);
    unsigned int sa0 = scv.x & 0xffffu, sa1 = scv.x >> 16;
    unsigned int sa2 = scv.y & 0xffffu, sa3 = scv.y >> 16;
    unsigned int sa4 = scv.z & 0xffffu, sa5 = scv.z >> 16;
    unsigned int sa6 = scv.w & 0xffffu, sa7 = scv.w >> 16;
    unsigned int pre = 0;
    pre += (wv > 0) ? sa0 : 0u;
    pre += (wv > 1) ? sa1 : 0u;
    pre += (wv > 2) ? sa2 : 0u;
    pre += (wv > 3) ? sa3 : 0u;
    pre += (wv > 4) ? sa4 : 0u;
    pre += (wv > 5) ? sa5 : 0u;
    pre += (wv > 6) ? sa6 : 0u;
    (void)sa7;
    unsigned int base = rbm + pre;

    // all-ones bf16 B-fragment for MFMA row-sums
    short8 ones8;
#pragma unroll
    for (int k = 0; k < 8; ++k) ones8[k] = (short)0x3f80;

    f32x4 acc0 = {0.f,0.f,0.f,0.f}, acc1 = {0.f,0.f,0.f,0.f};
    f32x4 acc2 = {0.f,0.f,0.f,0.f}, acc3 = {0.f,0.f,0.f,0.f};
    f32x4 acc4 = {0.f,0.f,0.f,0.f};
    const short* hpm = hT + (size_t)m * N;

    for (int w = w0; w < w0 + SEGW; ++w) {
        unsigned long long w64 = brow[w];
#pragma unroll
        for (int hh = 0; hh < 2; ++hh) {
            int off = hh * 32 + g * 8;
            unsigned int n = (unsigned)__popcll(w64 & ((1ull << off) - 1ull));
            unsigned int u = (unsigned int)(w64 >> off) & 0xffu;
            float pf[8];
#pragma unroll
            for (int j = 0; j < 8; ++j) {
                unsigned int bit = (u >> j) & 1u;
                unsigned int r = base + n;
                float d = fdl[r & 8191u];
                float sv = (r >= Rstar) ? s1 : s0;
                float v = sv + d;
                float lr = fmaxf(v, 0.01f * v);     // leaky_relu (both signs)
                float p = exp2_fast(lr);
                pf[j] = bit ? p : 0.f;
                n += bit;
            }
            union { short8 v; unsigned q[4]; } afu;
#pragma unroll
            for (int k = 0; k < 4; ++k) {
                unsigned qk;
                asm("v_cvt_pk_bf16_f32 %0, %1, %2"
                    : "=v"(qk) : "v"(pf[2 * k]), "v"(pf[2 * k + 1]));
                afu.q[k] = qk;
            }
            const short* hp = hpm + w * 64 + off;
            short8 b0 = *(const short8*)(hp);
            short8 b1 = *(const short8*)(hp + 16 * N);
            short8 b2 = *(const short8*)(hp + 32 * N);
            short8 b3 = *(const short8*)(hp + 48 * N);
            acc0 = __builtin_amdgcn_mfma_f32_16x16x32_bf16(afu.v, b0, acc0, 0, 0, 0);
            acc1 = __builtin_amdgcn_mfma_f32_16x16x32_bf16(afu.v, b1, acc1, 0, 0, 0);
            acc2 = __builtin_amdgcn_mfma_f32_16x16x32_bf16(afu.v, b2, acc2, 0, 0, 0);
            acc3 = __builtin_amdgcn_mfma_f32_16x16x32_bf16(afu.v, b3, acc3, 0, 0, 0);
            acc4 = __builtin_amdgcn_mfma_f32_16x16x32_bf16(afu.v, ones8, acc4, 0, 0, 0);
        }
        base += (unsigned)__popcll(w64);
    }

    // row sums from the ones-MFMA: D cols are all identical; lanes with m==0
    // hold rowsum[g*4+reg] in acc4[reg].
    if (m == 0) {
#pragma unroll
        for (int reg = 0; reg < 4; ++reg)
            rsum[wv * 16 + g * 4 + reg] = acc4[reg];
    }

    // D tile layout: col = lane&15, row = (lane>>4)*4 + reg
    // waves 0-3 write their tiles; waves 4-7 accumulate into them (barriered)
    float* dw = &dred[(wv & 3) * 1024];
    if (wv < 4) {
#pragma unroll
        for (int reg = 0; reg < 4; ++reg) {
            int lrow = g * 4 + reg;
            dw[lrow * 64 + m     ] = acc0[reg];
            dw[lrow * 64 + m + 16] = acc1[reg];
            dw[lrow * 64 + m + 32] = acc2[reg];
            dw[lrow * 64 + m + 48] = acc3[reg];
        }
    }
    __syncthreads();
    if (wv >= 4) {
#pragma unroll
        for (int reg = 0; reg < 4; ++reg) {
            int lrow = g * 4 + reg;
            dw[lrow * 64 + m     ] += acc0[reg];
            dw[lrow * 64 + m + 16] += acc1[reg];
            dw[lrow * 64 + m + 32] += acc2[reg];
            dw[lrow * 64 + m + 48] += acc3[reg];
        }
    }
    __syncthreads();

    // reduce 4 tile-pairs, normalize, elu, store: 1024 outputs / 512 threads
#pragma unroll
    for (int qq = 0; qq < 2; ++qq) {
        int o = qq * 512 + t;
        int lrow = o >> 6, col = o & 63;
        float s = 0.f;
#pragma unroll
        for (int v4 = 0; v4 < 4; ++v4) s += dred[v4 * 1024 + o];
        float rs = 0.f;
#pragma unroll
        for (int v8 = 0; v8 < 8; ++v8) rs += rsum[v8 * 16 + lrow];
        int grow = m0 + lrow;
        float res;
        if (cnt[grow] == 0u) {
            // empty row: softmax over all -inf = uniform 1/N (never hit for
            // this input; kept for faithful semantics)
            float hs = 0.f;
            const short* hp = hT + (size_t)col * N;
            for (int j = 0; j < N; ++j) hs += bf2f(hp[j]);
            res = hs * (1.0f / 8192.0f);
        } else {
            res = s / rs;
        }
        out[(size_t)grow * NHID + col] = elu_f(res);
    }
}

// ---------------------------------------------------------------------------
extern "C" void kernel_launch(void* const* d_in, const int* in_sizes, int n_in,
                              void* d_out, int out_size, void* d_ws, size_t ws_size,
                              hipStream_t stream)
{
    const float* x   = (const float*)d_in[0];
    const int*   adj = (const int*)d_in[1];
    const float* Ww  = (const float*)d_in[2];
    const float* Wb  = (const float*)d_in[3];
    const float* a1  = (const float*)d_in[4];
    const float* a2  = (const float*)d_in[5];
    const float* ab  = (const float*)d_in[6];
    float* out = (float*)d_out;

    char* ws = (char*)d_ws;
    float* fs = (float*)(ws + 0);                          // 32 KB
    float* fd = (float*)(ws + 32768);                      // 32 KB
    unsigned int* cnt = (unsigned int*)(ws + 65536);       // 32 KB
    unsigned short* segcnt = (unsigned short*)(ws + 98304); // 128 KB
    short* hT = (short*)(ws + 98304 + 131072);             // 1 MB bf16 [64][8192]
    unsigned long long* bits = (unsigned long long*)(ws + 98304 + 131072 + 1048576); // 8 MB

    k01_prologue<<<N + N / 4, 256, 0, stream>>>(adj, bits, cnt, segcnt,
                                                x, Ww, Wb, a1, a2, hT, fs, fd);
    k4_mfma<<<N / 16, 512, 0, stream>>>(bits, cnt, segcnt, fs, fd, ab, hT, out);
}